// Round 4
// baseline (770.484 us; speedup 1.0000x reference)
//
#include <hip/hip_runtime.h>
#include <stdint.h>

#define T_TOK 2048
#define HDIM 1024
#define NEXP 8
#define IDIM 3584
#define MAXTILE 40

// ws layout (bytes)
#define WS_CNT   0
#define WS_BASE  64
#define WS_TE    128
#define WS_TM    384
#define WS_NT    640
#define WS_TOK   704
#define WS_GW    (WS_TOK + NEXP * T_TOK * 4)
#define WS_XB    (WS_GW + NEXP * T_TOK * 4)
#define WS_G     (WS_XB + T_TOK * HDIM * 2)
// g: 4096 pairs x IDIM bf16 = 29,360,128 B ; total ~33.7 MB

typedef __attribute__((ext_vector_type(8))) short bf16x8;
typedef __attribute__((ext_vector_type(16))) float f32x16;

__device__ __forceinline__ unsigned short f2bf(float f) {
    union { float f; unsigned int u; } a; a.f = f;
    unsigned int u = a.u;
    return (unsigned short)((u + 0x7fffu + ((u >> 16) & 1u)) >> 16);
}

// packed fp32->bf16 RNE, 2 elems / instr (no builtin on gfx950; non-volatile
// so the scheduler may reorder freely)
__device__ __forceinline__ unsigned int cvt_pk_bf16(float lo, float hi) {
    unsigned int r;
    asm("v_cvt_pk_bf16_f32 %0, %1, %2" : "=v"(r) : "v"(lo), "v"(hi));
    return r;
}

__device__ __forceinline__ uint4 pack8(const float4 a, const float4 b) {
    uint4 r;
    r.x = cvt_pk_bf16(a.x, a.y);
    r.y = cvt_pk_bf16(a.z, a.w);
    r.z = cvt_pk_bf16(b.x, b.y);
    r.w = cvt_pk_bf16(b.z, b.w);
    return r;
}

__global__ __launch_bounds__(256) void xcvt_kernel(
    const float* __restrict__ x, unsigned short* __restrict__ xb)
{
    int i = (blockIdx.x * 256 + threadIdx.x) * 8;
    float4 a = *(const float4*)(x + i);
    float4 b = *(const float4*)(x + i + 4);
    *(uint4*)(xb + i) = pack8(a, b);
}

__global__ __launch_bounds__(256) void router_kernel(
    const float* __restrict__ x, const float* __restrict__ gate_w,
    int* __restrict__ cnt, int* __restrict__ tok, float* __restrict__ gw)
{
    int t = blockIdx.x * 4 + (threadIdx.x >> 6);
    int lane = threadIdx.x & 63;
    if (t >= T_TOK) return;
    const float* xr = x + (size_t)t * HDIM;
    float part[NEXP];
#pragma unroll
    for (int e = 0; e < NEXP; e++) part[e] = 0.f;
    for (int h = lane; h < HDIM; h += 64) {
        float xv = xr[h];
#pragma unroll
        for (int e = 0; e < NEXP; e++) part[e] += xv * gate_w[e * HDIM + h];
    }
#pragma unroll
    for (int e = 0; e < NEXP; e++) {
        float v = part[e];
#pragma unroll
        for (int o = 32; o > 0; o >>= 1) v += __shfl_xor(v, o);
        part[e] = v;
    }
    if (lane == 0) {
        int i0 = 0; float v0 = part[0];
#pragma unroll
        for (int e = 1; e < NEXP; e++) if (part[e] > v0) { v0 = part[e]; i0 = e; }
        int i1 = -1; float v1 = -3.4e38f;
#pragma unroll
        for (int e = 0; e < NEXP; e++) if (e != i0 && part[e] > v1) { v1 = part[e]; i1 = e; }
        float d = __expf(v1 - v0);
        float w1v = d / (1.f + d);
        float w0v = 1.f - w1v;
        int p0 = atomicAdd(&cnt[i0], 1);
        tok[i0 * T_TOK + p0] = t; gw[i0 * T_TOK + p0] = w0v;
        int p1 = atomicAdd(&cnt[i1], 1);
        tok[i1 * T_TOK + p1] = t; gw[i1 * T_TOK + p1] = w1v;
    }
}

__global__ void scan_kernel(const int* __restrict__ cnt, int* __restrict__ base,
                            int* __restrict__ tileE, int* __restrict__ tileM,
                            int* __restrict__ ntot)
{
    if (threadIdx.x == 0) {
        int s = 0, nt = 0;
        for (int e = 0; e < NEXP; e++) {
            base[e] = s; s += cnt[e];
            for (int m0 = 0; m0 < cnt[e]; m0 += 128) {
                tileE[nt] = e; tileM[nt] = m0; nt++;
            }
        }
        *ntot = nt;
    }
}

// ffn1: g = silu(x@w1^T) * (x@w3^T). Tile 128 tok x 128 i, BK=64.
__global__ __launch_bounds__(256, 3) void ffn1_mfma(
    const unsigned short* __restrict__ xb,
    const float* __restrict__ w1,
    const float* __restrict__ w3,
    const int* __restrict__ cnt, const int* __restrict__ base,
    const int* __restrict__ tok,
    const int* __restrict__ tileE, const int* __restrict__ tileM,
    const int* __restrict__ ntot,
    unsigned short* __restrict__ g)
{
    const int ti = blockIdx.y;
    if (ti >= *ntot) return;
    const int e = tileE[ti];
    const int m0 = tileM[ti];
    const int cntE = cnt[e];
    const int i0 = blockIdx.x * 128;
    const int tid = threadIdx.x;
    const int lane = tid & 63;
    const int wid = tid >> 6;

    __shared__ __align__(16) unsigned char lds[49152]; // xs 16K | w1s 16K | w3s 16K
    __shared__ int toks_s[128];
    if (tid < 128) toks_s[tid] = tok[e * T_TOK + min(m0 + tid, cntE - 1)];
    __syncthreads();

    const int rw = tid >> 3;              // staging row 0..31
    const int kc = tid & 7;               // 16B chunk in row
    const unsigned int dcol = ((unsigned)(kc * 16)) ^ ((unsigned)((rw & 7) << 4));

    int tk[4];
#pragma unroll
    for (int j = 0; j < 4; j++) tk[j] = toks_s[rw + 32 * j];

    const float* w1e = w1 + ((size_t)e * IDIM + i0) * HDIM;
    const float* w3e = w3 + ((size_t)e * IDIM + i0) * HDIM;

    const unsigned int XS = 0, W1S = 16384, W3S = 32768;

    f32x16 acc1[2][2], acc3[2][2];
#pragma unroll
    for (int a = 0; a < 2; a++)
#pragma unroll
        for (int b = 0; b < 2; b++)
#pragma unroll
            for (int r = 0; r < 16; r++) { acc1[a][b][r] = 0.f; acc3[a][b][r] = 0.f; }

    const int wr = wid >> 1;              // token half (0/1)
    const int wc = wid & 1;               // i half (0/1)
    const unsigned int lrow = (unsigned)(lane & 31);
    const unsigned int lswz = (lrow & 7) << 4;
    const unsigned int hi16 = (unsigned)((lane >> 5) * 16);
    const unsigned int aBase  = XS  + (wr * 64 + lrow) * 128;
    const unsigned int b1Base = W1S + (wc * 64 + lrow) * 128;
    const unsigned int b3Base = W3S + (wc * 64 + lrow) * 128;

    for (int k0 = 0; k0 < HDIM; k0 += 64) {
        uint4 xv[4]; float4 wva[4][2], wvb[4][2];
#pragma unroll
        for (int j = 0; j < 4; j++)
            xv[j] = *(const uint4*)(xb + (size_t)tk[j] * HDIM + k0 + kc * 8);
#pragma unroll
        for (int j = 0; j < 4; j++) {
            const float* s1 = w1e + (size_t)(rw + 32 * j) * HDIM + k0 + kc * 8;
            wva[j][0] = *(const float4*)s1;
            wva[j][1] = *(const float4*)(s1 + 4);
            const float* s3 = w3e + (size_t)(rw + 32 * j) * HDIM + k0 + kc * 8;
            wvb[j][0] = *(const float4*)s3;
            wvb[j][1] = *(const float4*)(s3 + 4);
        }
        __syncthreads();   // prev iter's LDS reads done
#pragma unroll
        for (int j = 0; j < 4; j++)
            *(uint4*)(lds + XS + (rw + 32 * j) * 128 + dcol) = xv[j];
#pragma unroll
        for (int j = 0; j < 4; j++) {
            *(uint4*)(lds + W1S + (rw + 32 * j) * 128 + dcol) = pack8(wva[j][0], wva[j][1]);
            *(uint4*)(lds + W3S + (rw + 32 * j) * 128 + dcol) = pack8(wvb[j][0], wvb[j][1]);
        }
        __syncthreads();
#pragma unroll
        for (int s = 0; s < 4; s++) {
            const unsigned int off = ((unsigned)(s * 32) + hi16) ^ lswz;
            bf16x8 a0 = *(const bf16x8*)(lds + aBase + off);
            bf16x8 a1 = *(const bf16x8*)(lds + aBase + 32 * 128 + off);
            bf16x8 p0 = *(const bf16x8*)(lds + b1Base + off);
            bf16x8 p1 = *(const bf16x8*)(lds + b1Base + 32 * 128 + off);
            bf16x8 q0 = *(const bf16x8*)(lds + b3Base + off);
            bf16x8 q1 = *(const bf16x8*)(lds + b3Base + 32 * 128 + off);
            acc1[0][0] = __builtin_amdgcn_mfma_f32_32x32x16_bf16(a0, p0, acc1[0][0], 0, 0, 0);
            acc1[0][1] = __builtin_amdgcn_mfma_f32_32x32x16_bf16(a0, p1, acc1[0][1], 0, 0, 0);
            acc1[1][0] = __builtin_amdgcn_mfma_f32_32x32x16_bf16(a1, p0, acc1[1][0], 0, 0, 0);
            acc1[1][1] = __builtin_amdgcn_mfma_f32_32x32x16_bf16(a1, p1, acc1[1][1], 0, 0, 0);
            acc3[0][0] = __builtin_amdgcn_mfma_f32_32x32x16_bf16(a0, q0, acc3[0][0], 0, 0, 0);
            acc3[0][1] = __builtin_amdgcn_mfma_f32_32x32x16_bf16(a0, q1, acc3[0][1], 0, 0, 0);
            acc3[1][0] = __builtin_amdgcn_mfma_f32_32x32x16_bf16(a1, q0, acc3[1][0], 0, 0, 0);
            acc3[1][1] = __builtin_amdgcn_mfma_f32_32x32x16_bf16(a1, q1, acc3[1][1], 0, 0, 0);
        }
    }

    const int pbase = base[e] + m0;
    const int rbase = 4 * (lane >> 5);
#pragma unroll
    for (int ma = 0; ma < 2; ma++) {
#pragma unroll
        for (int r = 0; r < 16; r++) {
            int row = (r & 3) + 8 * (r >> 2) + rbase;
            int m = wr * 64 + ma * 32 + row;
            if (m0 + m < cntE) {
                unsigned short* grow = g + (size_t)(pbase + m) * IDIM + i0 + wc * 64 + lrow;
#pragma unroll
                for (int nb = 0; nb < 2; nb++) {
                    float h1 = acc1[ma][nb][r], h3 = acc3[ma][nb][r];
                    float v = (h1 / (1.f + __expf(-h1))) * h3;
                    grow[nb * 32] = f2bf(v);
                }
            }
        }
    }
}

// ffn2: out[t,h] += gate * (g @ w2^T). Tile 128 pairs x 128 h, split-K x4 over IDIM.
__global__ __launch_bounds__(256, 4) void ffn2_mfma(
    const unsigned short* __restrict__ g,
    const float* __restrict__ w2,
    const int* __restrict__ cnt, const int* __restrict__ base,
    const int* __restrict__ tok, const float* __restrict__ gw,
    const int* __restrict__ tileE, const int* __restrict__ tileM,
    const int* __restrict__ ntot,
    float* __restrict__ out)
{
    const int ti = blockIdx.y;
    if (ti >= *ntot) return;
    const int e = tileE[ti];
    const int m0 = tileM[ti];
    const int cntE = cnt[e];
    const int ks = blockIdx.x >> 3;
    const int h0 = (blockIdx.x & 7) * 128;
    const int tid = threadIdx.x;
    const int lane = tid & 63;
    const int wid = tid >> 6;

    __shared__ __align__(16) unsigned char lds[32768]; // gs 16K | w2s 16K
    __shared__ int toks_s[128];
    __shared__ float gws_s[128];
    if (tid < 128) {
        int idx = e * T_TOK + min(m0 + tid, cntE - 1);
        toks_s[tid] = tok[idx];
        gws_s[tid] = gw[idx];
    }
    __syncthreads();

    const int rw = tid >> 3;
    const int kc = tid & 7;
    const unsigned int dcol = ((unsigned)(kc * 16)) ^ ((unsigned)((rw & 7) << 4));

    size_t gp[4];
    const int be = base[e];
#pragma unroll
    for (int j = 0; j < 4; j++)
        gp[j] = (size_t)(be + min(m0 + rw + 32 * j, cntE - 1)) * IDIM;

    const float* w2e = w2 + ((size_t)e * HDIM + h0) * IDIM;

    const unsigned int GS = 0, W2S = 16384;

    f32x16 acc[2][2];
#pragma unroll
    for (int a = 0; a < 2; a++)
#pragma unroll
        for (int b = 0; b < 2; b++)
#pragma unroll
            for (int r = 0; r < 16; r++) acc[a][b][r] = 0.f;

    const int wr = wid >> 1;
    const int wc = wid & 1;
    const unsigned int lrow = (unsigned)(lane & 31);
    const unsigned int lswz = (lrow & 7) << 4;
    const unsigned int hi16 = (unsigned)((lane >> 5) * 16);
    const unsigned int aBase = GS  + (wr * 64 + lrow) * 128;
    const unsigned int bBase = W2S + (wc * 64 + lrow) * 128;

    const int kbeg = ks * (IDIM / 4);
    const int kend = kbeg + (IDIM / 4);
    for (int k0 = kbeg; k0 < kend; k0 += 64) {
        uint4 gv[4]; float4 wv[4][2];
#pragma unroll
        for (int j = 0; j < 4; j++)
            gv[j] = *(const uint4*)(g + gp[j] + k0 + kc * 8);
#pragma unroll
        for (int j = 0; j < 4; j++) {
            const float* s = w2e + (size_t)(rw + 32 * j) * IDIM + k0 + kc * 8;
            wv[j][0] = *(const float4*)s;
            wv[j][1] = *(const float4*)(s + 4);
        }
        __syncthreads();
#pragma unroll
        for (int j = 0; j < 4; j++)
            *(uint4*)(lds + GS + (rw + 32 * j) * 128 + dcol) = gv[j];
#pragma unroll
        for (int j = 0; j < 4; j++)
            *(uint4*)(lds + W2S + (rw + 32 * j) * 128 + dcol) = pack8(wv[j][0], wv[j][1]);
        __syncthreads();
#pragma unroll
        for (int s = 0; s < 4; s++) {
            const unsigned int off = ((unsigned)(s * 32) + hi16) ^ lswz;
            bf16x8 a0 = *(const bf16x8*)(lds + aBase + off);
            bf16x8 a1 = *(const bf16x8*)(lds + aBase + 32 * 128 + off);
            bf16x8 b0 = *(const bf16x8*)(lds + bBase + off);
            bf16x8 b1 = *(const bf16x8*)(lds + bBase + 32 * 128 + off);
            acc[0][0] = __builtin_amdgcn_mfma_f32_32x32x16_bf16(a0, b0, acc[0][0], 0, 0, 0);
            acc[0][1] = __builtin_amdgcn_mfma_f32_32x32x16_bf16(a0, b1, acc[0][1], 0, 0, 0);
            acc[1][0] = __builtin_amdgcn_mfma_f32_32x32x16_bf16(a1, b0, acc[1][0], 0, 0, 0);
            acc[1][1] = __builtin_amdgcn_mfma_f32_32x32x16_bf16(a1, b1, acc[1][1], 0, 0, 0);
        }
    }

    const int rbase = 4 * (lane >> 5);
#pragma unroll
    for (int ma = 0; ma < 2; ma++) {
#pragma unroll
        for (int r = 0; r < 16; r++) {
            int row = (r & 3) + 8 * (r >> 2) + rbase;
            int m = wr * 64 + ma * 32 + row;
            if (m0 + m < cntE) {
                int t = toks_s[m];
                float wgt = gws_s[m];
                float* orow = out + (size_t)t * HDIM + h0 + wc * 64 + lrow;
                atomicAdd(&orow[0],  wgt * acc[ma][0][r]);
                atomicAdd(&orow[32], wgt * acc[ma][1][r]);
            }
        }
    }
}

extern "C" void kernel_launch(void* const* d_in, const int* in_sizes, int n_in,
                              void* d_out, int out_size, void* d_ws, size_t ws_size,
                              hipStream_t stream) {
    const float* x      = (const float*)d_in[0];
    const float* gate_w = (const float*)d_in[1];
    const float* w1     = (const float*)d_in[2];
    const float* w2     = (const float*)d_in[3];
    const float* w3     = (const float*)d_in[4];
    float* out = (float*)d_out;
    char* ws = (char*)d_ws;
    int* cnt   = (int*)(ws + WS_CNT);
    int* base  = (int*)(ws + WS_BASE);
    int* tileE = (int*)(ws + WS_TE);
    int* tileM = (int*)(ws + WS_TM);
    int* ntot  = (int*)(ws + WS_NT);
    int* tok   = (int*)(ws + WS_TOK);
    float* gw  = (float*)(ws + WS_GW);
    unsigned short* xb = (unsigned short*)(ws + WS_XB);
    unsigned short* g  = (unsigned short*)(ws + WS_G);

    hipMemsetAsync(cnt, 0, 64, stream);
    hipMemsetAsync(d_out, 0, (size_t)out_size * sizeof(float), stream);

    xcvt_kernel<<<T_TOK * HDIM / (256 * 8), 256, 0, stream>>>(x, xb);
    router_kernel<<<T_TOK / 4, 256, 0, stream>>>(x, gate_w, cnt, tok, gw);
    scan_kernel<<<1, 64, 0, stream>>>(cnt, base, tileE, tileM, ntot);
    ffn1_mfma<<<dim3(IDIM / 128, MAXTILE), 256, 0, stream>>>(xb, w1, w3, cnt, base, tok, tileE, tileM, ntot, g);
    ffn2_mfma<<<dim3(32, MAXTILE), 256, 0, stream>>>(g, w2, cnt, base, tok, gw, tileE, tileM, ntot, out);
}

// Round 5
// 464.690 us; speedup vs baseline: 1.6581x; 1.6581x over previous
//
#include <hip/hip_runtime.h>
#include <stdint.h>

#define T_TOK 2048
#define HDIM 1024
#define NEXP 8
#define IDIM 3584
#define MAXTILE 40

// ws layout (bytes)
#define WS_CNT   0
#define WS_BASE  64
#define WS_TE    128
#define WS_TM    384
#define WS_NT    640
#define WS_TOK   704
#define WS_GW    (WS_TOK + NEXP * T_TOK * 4)
#define WS_XB    (WS_GW + NEXP * T_TOK * 4)
#define WS_G     (WS_XB + T_TOK * HDIM * 2)
// g: 4096 pairs x IDIM bf16 = 29,360,128 B ; total ~33.7 MB

typedef __attribute__((ext_vector_type(8))) short bf16x8;
typedef __attribute__((ext_vector_type(16))) float f32x16;

__device__ __forceinline__ unsigned short f2bf(float f) {
    union { float f; unsigned int u; } a; a.f = f;
    unsigned int u = a.u;
    return (unsigned short)((u + 0x7fffu + ((u >> 16) & 1u)) >> 16);
}

// packed fp32->bf16 RNE, 2 elems / instr
__device__ __forceinline__ unsigned int cvt_pk_bf16(float lo, float hi) {
    unsigned int r;
    asm("v_cvt_pk_bf16_f32 %0, %1, %2" : "=v"(r) : "v"(lo), "v"(hi));
    return r;
}

__device__ __forceinline__ uint4 pack8(const float4 a, const float4 b) {
    uint4 r;
    r.x = cvt_pk_bf16(a.x, a.y);
    r.y = cvt_pk_bf16(a.z, a.w);
    r.z = cvt_pk_bf16(b.x, b.y);
    r.w = cvt_pk_bf16(b.z, b.w);
    return r;
}

__global__ __launch_bounds__(256) void xcvt_kernel(
    const float* __restrict__ x, unsigned short* __restrict__ xb)
{
    int i = (blockIdx.x * 256 + threadIdx.x) * 8;
    float4 a = *(const float4*)(x + i);
    float4 b = *(const float4*)(x + i + 4);
    *(uint4*)(xb + i) = pack8(a, b);
}

__global__ __launch_bounds__(256) void router_kernel(
    const float* __restrict__ x, const float* __restrict__ gate_w,
    int* __restrict__ cnt, int* __restrict__ tok, float* __restrict__ gw)
{
    int t = blockIdx.x * 4 + (threadIdx.x >> 6);
    int lane = threadIdx.x & 63;
    if (t >= T_TOK) return;
    const float* xr = x + (size_t)t * HDIM;
    float part[NEXP];
#pragma unroll
    for (int e = 0; e < NEXP; e++) part[e] = 0.f;
    for (int h = lane; h < HDIM; h += 64) {
        float xv = xr[h];
#pragma unroll
        for (int e = 0; e < NEXP; e++) part[e] += xv * gate_w[e * HDIM + h];
    }
#pragma unroll
    for (int e = 0; e < NEXP; e++) {
        float v = part[e];
#pragma unroll
        for (int o = 32; o > 0; o >>= 1) v += __shfl_xor(v, o);
        part[e] = v;
    }
    if (lane == 0) {
        int i0 = 0; float v0 = part[0];
#pragma unroll
        for (int e = 1; e < NEXP; e++) if (part[e] > v0) { v0 = part[e]; i0 = e; }
        int i1 = -1; float v1 = -3.4e38f;
#pragma unroll
        for (int e = 0; e < NEXP; e++) if (e != i0 && part[e] > v1) { v1 = part[e]; i1 = e; }
        float d = __expf(v1 - v0);
        float w1v = d / (1.f + d);
        float w0v = 1.f - w1v;
        int p0 = atomicAdd(&cnt[i0], 1);
        tok[i0 * T_TOK + p0] = t; gw[i0 * T_TOK + p0] = w0v;
        int p1 = atomicAdd(&cnt[i1], 1);
        tok[i1 * T_TOK + p1] = t; gw[i1 * T_TOK + p1] = w1v;
    }
}

__global__ void scan_kernel(const int* __restrict__ cnt, int* __restrict__ base,
                            int* __restrict__ tileE, int* __restrict__ tileM,
                            int* __restrict__ ntot)
{
    if (threadIdx.x == 0) {
        int s = 0, nt = 0;
        for (int e = 0; e < NEXP; e++) {
            base[e] = s; s += cnt[e];
            for (int m0 = 0; m0 < cnt[e]; m0 += 128) {
                tileE[nt] = e; tileM[nt] = m0; nt++;
            }
        }
        *ntot = nt;
    }
}

// ffn1: g = silu(x@w1^T) * (x@w3^T). Tile 128 tok x 128 i, BK=64, 2-phase reg prefetch.
__global__ __launch_bounds__(256, 2) void ffn1_mfma(
    const unsigned short* __restrict__ xb,
    const float* __restrict__ w1,
    const float* __restrict__ w3,
    const int* __restrict__ cnt, const int* __restrict__ base,
    const int* __restrict__ tok,
    const int* __restrict__ tileE, const int* __restrict__ tileM,
    const int* __restrict__ ntot,
    unsigned short* __restrict__ g)
{
    const int ti = blockIdx.y;
    if (ti >= *ntot) return;
    const int e = tileE[ti];
    const int m0 = tileM[ti];
    const int cntE = cnt[e];
    const int i0 = blockIdx.x * 128;
    const int tid = threadIdx.x;
    const int lane = tid & 63;
    const int wid = tid >> 6;

    __shared__ __align__(16) unsigned char lds[49152]; // xs 16K | w1s 16K | w3s 16K
    __shared__ int toks_s[128];
    if (tid < 128) toks_s[tid] = tok[e * T_TOK + min(m0 + tid, cntE - 1)];
    __syncthreads();

    const int rw = tid >> 3;              // staging row 0..31
    const int kc = tid & 7;               // 16B chunk in row
    const unsigned int dcol = ((unsigned)(kc * 16)) ^ ((unsigned)((rw & 7) << 4));

    int tk[4];
#pragma unroll
    for (int j = 0; j < 4; j++) tk[j] = toks_s[rw + 32 * j];

    const float* w1e = w1 + ((size_t)e * IDIM + i0) * HDIM;
    const float* w3e = w3 + ((size_t)e * IDIM + i0) * HDIM;

    const unsigned int XS = 0, W1S = 16384, W3S = 32768;

    f32x16 acc1[2][2], acc3[2][2];
#pragma unroll
    for (int a = 0; a < 2; a++)
#pragma unroll
        for (int b = 0; b < 2; b++)
#pragma unroll
            for (int r = 0; r < 16; r++) { acc1[a][b][r] = 0.f; acc3[a][b][r] = 0.f; }

    const int wr = wid >> 1;              // token half (0/1)
    const int wc = wid & 1;               // i half (0/1)
    const unsigned int lrow = (unsigned)(lane & 31);
    const unsigned int lswz = (lrow & 7) << 4;
    const unsigned int hi16 = (unsigned)((lane >> 5) * 16);
    const unsigned int aBase  = XS  + (wr * 64 + lrow) * 128;
    const unsigned int b1Base = W1S + (wc * 64 + lrow) * 128;
    const unsigned int b3Base = W3S + (wc * 64 + lrow) * 128;

    // staging registers (carried across iterations)
    uint4 xv[4]; float4 wva[4][2], wvb[4][2];

    // prologue: load k0 = 0
#pragma unroll
    for (int j = 0; j < 4; j++)
        xv[j] = *(const uint4*)(xb + (size_t)tk[j] * HDIM + kc * 8);
#pragma unroll
    for (int j = 0; j < 4; j++) {
        const float* s1 = w1e + (size_t)(rw + 32 * j) * HDIM + kc * 8;
        wva[j][0] = *(const float4*)s1;
        wva[j][1] = *(const float4*)(s1 + 4);
        const float* s3 = w3e + (size_t)(rw + 32 * j) * HDIM + kc * 8;
        wvb[j][0] = *(const float4*)s3;
        wvb[j][1] = *(const float4*)(s3 + 4);
    }

    for (int k0 = 0; k0 < HDIM; k0 += 64) {
        __syncthreads();   // previous iter's LDS reads complete
#pragma unroll
        for (int j = 0; j < 4; j++)
            *(uint4*)(lds + XS + (rw + 32 * j) * 128 + dcol) = xv[j];
#pragma unroll
        for (int j = 0; j < 4; j++) {
            *(uint4*)(lds + W1S + (rw + 32 * j) * 128 + dcol) = pack8(wva[j][0], wva[j][1]);
            *(uint4*)(lds + W3S + (rw + 32 * j) * 128 + dcol) = pack8(wvb[j][0], wvb[j][1]);
        }
        __syncthreads();   // LDS writes visible

        // issue NEXT iteration's global loads — they fly under the MFMAs below
        if (k0 + 64 < HDIM) {
            const int kn = k0 + 64;
#pragma unroll
            for (int j = 0; j < 4; j++)
                xv[j] = *(const uint4*)(xb + (size_t)tk[j] * HDIM + kn + kc * 8);
#pragma unroll
            for (int j = 0; j < 4; j++) {
                const float* s1 = w1e + (size_t)(rw + 32 * j) * HDIM + kn + kc * 8;
                wva[j][0] = *(const float4*)s1;
                wva[j][1] = *(const float4*)(s1 + 4);
                const float* s3 = w3e + (size_t)(rw + 32 * j) * HDIM + kn + kc * 8;
                wvb[j][0] = *(const float4*)s3;
                wvb[j][1] = *(const float4*)(s3 + 4);
            }
        }

#pragma unroll
        for (int s = 0; s < 4; s++) {
            const unsigned int off = ((unsigned)(s * 32) + hi16) ^ lswz;
            bf16x8 a0 = *(const bf16x8*)(lds + aBase + off);
            bf16x8 a1 = *(const bf16x8*)(lds + aBase + 32 * 128 + off);
            bf16x8 p0 = *(const bf16x8*)(lds + b1Base + off);
            bf16x8 p1 = *(const bf16x8*)(lds + b1Base + 32 * 128 + off);
            bf16x8 q0 = *(const bf16x8*)(lds + b3Base + off);
            bf16x8 q1 = *(const bf16x8*)(lds + b3Base + 32 * 128 + off);
            acc1[0][0] = __builtin_amdgcn_mfma_f32_32x32x16_bf16(a0, p0, acc1[0][0], 0, 0, 0);
            acc1[0][1] = __builtin_amdgcn_mfma_f32_32x32x16_bf16(a0, p1, acc1[0][1], 0, 0, 0);
            acc1[1][0] = __builtin_amdgcn_mfma_f32_32x32x16_bf16(a1, p0, acc1[1][0], 0, 0, 0);
            acc1[1][1] = __builtin_amdgcn_mfma_f32_32x32x16_bf16(a1, p1, acc1[1][1], 0, 0, 0);
            acc3[0][0] = __builtin_amdgcn_mfma_f32_32x32x16_bf16(a0, q0, acc3[0][0], 0, 0, 0);
            acc3[0][1] = __builtin_amdgcn_mfma_f32_32x32x16_bf16(a0, q1, acc3[0][1], 0, 0, 0);
            acc3[1][0] = __builtin_amdgcn_mfma_f32_32x32x16_bf16(a1, q0, acc3[1][0], 0, 0, 0);
            acc3[1][1] = __builtin_amdgcn_mfma_f32_32x32x16_bf16(a1, q1, acc3[1][1], 0, 0, 0);
        }
    }

    const int pbase = base[e] + m0;
    const int rbase = 4 * (lane >> 5);
#pragma unroll
    for (int ma = 0; ma < 2; ma++) {
#pragma unroll
        for (int r = 0; r < 16; r++) {
            int row = (r & 3) + 8 * (r >> 2) + rbase;
            int m = wr * 64 + ma * 32 + row;
            if (m0 + m < cntE) {
                unsigned short* grow = g + (size_t)(pbase + m) * IDIM + i0 + wc * 64 + lrow;
#pragma unroll
                for (int nb = 0; nb < 2; nb++) {
                    float h1 = acc1[ma][nb][r], h3 = acc3[ma][nb][r];
                    float v = (h1 / (1.f + __expf(-h1))) * h3;
                    grow[nb * 32] = f2bf(v);
                }
            }
        }
    }
}

// ffn2: out[t,h] += gate * (g @ w2^T). Tile 128 pairs x 128 h, split-K x4, 2-phase reg prefetch.
__global__ __launch_bounds__(256, 2) void ffn2_mfma(
    const unsigned short* __restrict__ g,
    const float* __restrict__ w2,
    const int* __restrict__ cnt, const int* __restrict__ base,
    const int* __restrict__ tok, const float* __restrict__ gw,
    const int* __restrict__ tileE, const int* __restrict__ tileM,
    const int* __restrict__ ntot,
    float* __restrict__ out)
{
    const int ti = blockIdx.y;
    if (ti >= *ntot) return;
    const int e = tileE[ti];
    const int m0 = tileM[ti];
    const int cntE = cnt[e];
    const int ks = blockIdx.x >> 3;
    const int h0 = (blockIdx.x & 7) * 128;
    const int tid = threadIdx.x;
    const int lane = tid & 63;
    const int wid = tid >> 6;

    __shared__ __align__(16) unsigned char lds[32768]; // gs 16K | w2s 16K
    __shared__ int toks_s[128];
    __shared__ float gws_s[128];
    if (tid < 128) {
        int idx = e * T_TOK + min(m0 + tid, cntE - 1);
        toks_s[tid] = tok[idx];
        gws_s[tid] = gw[idx];
    }
    __syncthreads();

    const int rw = tid >> 3;
    const int kc = tid & 7;
    const unsigned int dcol = ((unsigned)(kc * 16)) ^ ((unsigned)((rw & 7) << 4));

    size_t gp[4];
    const int be = base[e];
#pragma unroll
    for (int j = 0; j < 4; j++)
        gp[j] = (size_t)(be + min(m0 + rw + 32 * j, cntE - 1)) * IDIM;

    const float* w2e = w2 + ((size_t)e * HDIM + h0) * IDIM;

    const unsigned int GS = 0, W2S = 16384;

    f32x16 acc[2][2];
#pragma unroll
    for (int a = 0; a < 2; a++)
#pragma unroll
        for (int b = 0; b < 2; b++)
#pragma unroll
            for (int r = 0; r < 16; r++) acc[a][b][r] = 0.f;

    const int wr = wid >> 1;
    const int wc = wid & 1;
    const unsigned int lrow = (unsigned)(lane & 31);
    const unsigned int lswz = (lrow & 7) << 4;
    const unsigned int hi16 = (unsigned)((lane >> 5) * 16);
    const unsigned int aBase = GS  + (wr * 64 + lrow) * 128;
    const unsigned int bBase = W2S + (wc * 64 + lrow) * 128;

    const int kbeg = ks * (IDIM / 4);
    const int kend = kbeg + (IDIM / 4);

    uint4 gv[4]; float4 wv[4][2];
#pragma unroll
    for (int j = 0; j < 4; j++)
        gv[j] = *(const uint4*)(g + gp[j] + kbeg + kc * 8);
#pragma unroll
    for (int j = 0; j < 4; j++) {
        const float* s = w2e + (size_t)(rw + 32 * j) * IDIM + kbeg + kc * 8;
        wv[j][0] = *(const float4*)s;
        wv[j][1] = *(const float4*)(s + 4);
    }

    for (int k0 = kbeg; k0 < kend; k0 += 64) {
        __syncthreads();
#pragma unroll
        for (int j = 0; j < 4; j++)
            *(uint4*)(lds + GS + (rw + 32 * j) * 128 + dcol) = gv[j];
#pragma unroll
        for (int j = 0; j < 4; j++)
            *(uint4*)(lds + W2S + (rw + 32 * j) * 128 + dcol) = pack8(wv[j][0], wv[j][1]);
        __syncthreads();

        if (k0 + 64 < kend) {
            const int kn = k0 + 64;
#pragma unroll
            for (int j = 0; j < 4; j++)
                gv[j] = *(const uint4*)(g + gp[j] + kn + kc * 8);
#pragma unroll
            for (int j = 0; j < 4; j++) {
                const float* s = w2e + (size_t)(rw + 32 * j) * IDIM + kn + kc * 8;
                wv[j][0] = *(const float4*)s;
                wv[j][1] = *(const float4*)(s + 4);
            }
        }

#pragma unroll
        for (int s = 0; s < 4; s++) {
            const unsigned int off = ((unsigned)(s * 32) + hi16) ^ lswz;
            bf16x8 a0 = *(const bf16x8*)(lds + aBase + off);
            bf16x8 a1 = *(const bf16x8*)(lds + aBase + 32 * 128 + off);
            bf16x8 b0 = *(const bf16x8*)(lds + bBase + off);
            bf16x8 b1 = *(const bf16x8*)(lds + bBase + 32 * 128 + off);
            acc[0][0] = __builtin_amdgcn_mfma_f32_32x32x16_bf16(a0, b0, acc[0][0], 0, 0, 0);
            acc[0][1] = __builtin_amdgcn_mfma_f32_32x32x16_bf16(a0, b1, acc[0][1], 0, 0, 0);
            acc[1][0] = __builtin_amdgcn_mfma_f32_32x32x16_bf16(a1, b0, acc[1][0], 0, 0, 0);
            acc[1][1] = __builtin_amdgcn_mfma_f32_32x32x16_bf16(a1, b1, acc[1][1], 0, 0, 0);
        }
    }

    const int rbase = 4 * (lane >> 5);
#pragma unroll
    for (int ma = 0; ma < 2; ma++) {
#pragma unroll
        for (int r = 0; r < 16; r++) {
            int row = (r & 3) + 8 * (r >> 2) + rbase;
            int m = wr * 64 + ma * 32 + row;
            if (m0 + m < cntE) {
                int t = toks_s[m];
                float wgt = gws_s[m];
                float* orow = out + (size_t)t * HDIM + h0 + wc * 64 + lrow;
                atomicAdd(&orow[0],  wgt * acc[ma][0][r]);
                atomicAdd(&orow[32], wgt * acc[ma][1][r]);
            }
        }
    }
}

extern "C" void kernel_launch(void* const* d_in, const int* in_sizes, int n_in,
                              void* d_out, int out_size, void* d_ws, size_t ws_size,
                              hipStream_t stream) {
    const float* x      = (const float*)d_in[0];
    const float* gate_w = (const float*)d_in[1];
    const float* w1     = (const float*)d_in[2];
    const float* w2     = (const float*)d_in[3];
    const float* w3     = (const float*)d_in[4];
    float* out = (float*)d_out;
    char* ws = (char*)d_ws;
    int* cnt   = (int*)(ws + WS_CNT);
    int* base  = (int*)(ws + WS_BASE);
    int* tileE = (int*)(ws + WS_TE);
    int* tileM = (int*)(ws + WS_TM);
    int* ntot  = (int*)(ws + WS_NT);
    int* tok   = (int*)(ws + WS_TOK);
    float* gw  = (float*)(ws + WS_GW);
    unsigned short* xb = (unsigned short*)(ws + WS_XB);
    unsigned short* g  = (unsigned short*)(ws + WS_G);

    hipMemsetAsync(cnt, 0, 64, stream);
    hipMemsetAsync(d_out, 0, (size_t)out_size * sizeof(float), stream);

    xcvt_kernel<<<T_TOK * HDIM / (256 * 8), 256, 0, stream>>>(x, xb);
    router_kernel<<<T_TOK / 4, 256, 0, stream>>>(x, gate_w, cnt, tok, gw);
    scan_kernel<<<1, 64, 0, stream>>>(cnt, base, tileE, tileM, ntot);
    ffn1_mfma<<<dim3(IDIM / 128, MAXTILE), 256, 0, stream>>>(xb, w1, w3, cnt, base, tok, tileE, tileM, ntot, g);
    ffn2_mfma<<<dim3(32, MAXTILE), 256, 0, stream>>>(g, w2, cnt, base, tok, gw, tileE, tileM, ntot, out);
}